// Round 1
// baseline (249.109 us; speedup 1.0000x reference)
//
#include <hip/hip_runtime.h>

// Problem constants (fixed by the reference): K=64, C=128, H=W=512, N=150000.
// K and C are hardcoded; N/HW derived from in_sizes/out_size; W read on-device.
typedef float v2f __attribute__((ext_vector_type(2)));
typedef float v4f __attribute__((ext_vector_type(4)));

constexpr int KK = 64;
constexpr int CC = 128;

__global__ __launch_bounds__(256) void init_winner(int* __restrict__ winner, int HW) {
    int p = blockIdx.x * 256 + threadIdx.x;
    if (p < HW) winner[p] = -1;
}

__global__ __launch_bounds__(256) void scatter_winner(
        const int* __restrict__ pX, const int* __restrict__ pY,
        const int* __restrict__ pW, int* __restrict__ winner, int N) {
    int i = blockIdx.x * 256 + threadIdx.x;
    if (i < N) {
        int idx = pY[i] * pW[0] + pX[i];
        atomicMax(&winner[idx], i);  // numpy last-write-wins == max index wins
    }
}

// vertMask [K][N] -> vmT [N][K]; makes each point's column a contiguous,
// 256B-aligned 256B row so produce_T's gather has 100% cache-line utilization.
__global__ __launch_bounds__(256) void transpose_vm(
        const float* __restrict__ vm, float* __restrict__ vmT, int N) {
    __shared__ float tile[KK][KK + 1];
    int n0 = blockIdx.x * KK;
    int tx = threadIdx.x & 63;   // n within tile on load, k on store
    int ty = threadIdx.x >> 6;   // 0..3
    int n = n0 + tx;
    #pragma unroll
    for (int r = 0; r < 16; ++r) {
        int k = r * 4 + ty;
        tile[k][tx] = (n < N) ? vm[(size_t)k * N + n] : 0.f;  // coalesced read
    }
    __syncthreads();
    #pragma unroll
    for (int r = 0; r < 16; ++r) {
        int nl = r * 4 + ty;
        int nn = n0 + nl;
        if (nn < N) vmT[(size_t)nn * KK + tx] = tile[tx][nl];  // coalesced write
    }
}

// One thread per pixel: gather winner column (16B vec loads), 128 channel dots,
// coalesced channel-plane stores. Non-winner lanes use a zero column so the
// store stream is uniform (no divergent store path).
__global__ __launch_bounds__(256) void produce_T(
        const int* __restrict__ winner, const float* __restrict__ vmT,
        const float* __restrict__ feature, float* __restrict__ out, int HW) {
    int p = blockIdx.x * 256 + threadIdx.x;
    if (p >= HW) return;
    int w = winner[p];
    v2f col[KK / 2];
    if (w >= 0) {
        const v4f* src = reinterpret_cast<const v4f*>(vmT + (size_t)w * KK);
        #pragma unroll
        for (int q = 0; q < KK / 4; ++q) {
            v4f v = src[q];
            col[2 * q][0] = v[0];     col[2 * q][1] = v[1];
            col[2 * q + 1][0] = v[2]; col[2 * q + 1][1] = v[3];
        }
    } else {
        #pragma unroll
        for (int q = 0; q < KK / 2; ++q) { col[q][0] = 0.f; col[q][1] = 0.f; }
    }
    const v2f* f2 = reinterpret_cast<const v2f*>(feature);  // uniform -> s_load
    float* op = out + p;
    #pragma unroll 4
    for (int c = 0; c < CC; ++c) {
        v2f acc = {0.f, 0.f};
        #pragma unroll
        for (int q = 0; q < KK / 2; ++q) acc += f2[c * (KK / 2) + q] * col[q];
        op[(size_t)c * HW] = acc[0] + acc[1];
    }
}

// Fallback if d_ws can't hold the transposed vertMask: gather strided columns.
__global__ __launch_bounds__(256) void produce_direct(
        const int* __restrict__ winner, const float* __restrict__ vm,
        const float* __restrict__ feature, float* __restrict__ out,
        int HW, int N) {
    int p = blockIdx.x * 256 + threadIdx.x;
    if (p >= HW) return;
    int w = winner[p];
    float col[KK];
    if (w >= 0) {
        #pragma unroll
        for (int k = 0; k < KK; ++k) col[k] = vm[(size_t)k * N + w];
    } else {
        #pragma unroll
        for (int k = 0; k < KK; ++k) col[k] = 0.f;
    }
    float* op = out + p;
    #pragma unroll 4
    for (int c = 0; c < CC; ++c) {
        float acc = 0.f;
        const float* f = feature + c * KK;
        #pragma unroll
        for (int k = 0; k < KK; ++k) acc += f[k] * col[k];
        op[(size_t)c * HW] = acc;
    }
}

extern "C" void kernel_launch(void* const* d_in, const int* in_sizes, int n_in,
                              void* d_out, int out_size, void* d_ws, size_t ws_size,
                              hipStream_t stream) {
    // inputs: 0=H(1), 1=W(1), 2=pX(N), 3=pY(N), 4=vertMask(K*N), 5=feature(C*K)
    const int* dW = (const int*)d_in[1];
    const int* pX = (const int*)d_in[2];
    const int* pY = (const int*)d_in[3];
    const float* vm = (const float*)d_in[4];
    const float* feat = (const float*)d_in[5];
    float* out = (float*)d_out;

    int N = in_sizes[2];
    int HW = out_size / CC;  // 512*512 = 262144

    int* winner = (int*)d_ws;
    size_t winBytes = (((size_t)HW * sizeof(int)) + 255) & ~(size_t)255;
    float* vmT = (float*)((char*)d_ws + winBytes);
    bool useT = ws_size >= winBytes + (size_t)N * KK * sizeof(float);

    hipLaunchKernelGGL(init_winner, dim3((HW + 255) / 256), dim3(256), 0, stream,
                       winner, HW);
    hipLaunchKernelGGL(scatter_winner, dim3((N + 255) / 256), dim3(256), 0, stream,
                       pX, pY, dW, winner, N);
    if (useT) {
        hipLaunchKernelGGL(transpose_vm, dim3((N + KK - 1) / KK), dim3(256), 0, stream,
                           vm, vmT, N);
        hipLaunchKernelGGL(produce_T, dim3((HW + 255) / 256), dim3(256), 0, stream,
                           winner, vmT, feat, out, HW);
    } else {
        hipLaunchKernelGGL(produce_direct, dim3((HW + 255) / 256), dim3(256), 0, stream,
                           winner, vm, feat, out, HW, N);
    }
}